// Round 1
// baseline (848.170 us; speedup 1.0000x reference)
//
#include <hip/hip_runtime.h>
#include <math.h>

#define N_PIX 32768
#define DEG 9
#define BATCH 8
#define TILE 64

// One fused ChebConv layer (K=3):
//   T0 = X, T1 = L X, T2 = 2 L T1 - T0   (L = 9-point circulant stencil)
//   Y = [T0|T1|T2] @ W + b, optional ELU
// Block: 512 threads, one (64-row tile, batch) per block.
template<int FIN, int FOUT, bool ELU>
__global__ __launch_bounds__(512, 1)
void cheb_layer(const float* __restrict__ X,    // [B, N, FIN]
                const float* __restrict__ vals, // [N*9]
                const float* __restrict__ W,    // [3*FIN, FOUT]
                const float* __restrict__ bias, // [FOUT]
                float* __restrict__ Y)          // [B, N, FOUT]
{
    constexpr int LDA = FIN + 4;      // pad: stride*4B multiple of 16, banks 2-way max
    constexpr int XROWS = TILE + 16;  // halo 8 each side (two stencil applications)
    constexpr int T1ROWS = TILE + 8;  // halo 4 each side
    constexpr int FH = FIN / 2;       // per-group f-range within each segment

    __shared__ alignas(16) float Xs[XROWS * LDA];
    __shared__ alignas(16) float T1s[T1ROWS * LDA];
    __shared__ alignas(16) float T2s[TILE * LDA];
    __shared__ alignas(16) float Ws[3 * FIN * FOUT];
    __shared__ alignas(16) float Red[256 * 16];
    __shared__ float Bs[FOUT > 0 ? FOUT : 1];

    const int tid = threadIdx.x;
    const int n0 = blockIdx.x * TILE;
    const int b  = blockIdx.y;

    // stage W + bias
    for (int i = tid; i < 3 * FIN * FOUT; i += 512) Ws[i] = W[i];
    if (tid < FOUT) Bs[tid] = bias[tid];

    // stage X tile rows [n0-8, n0+TILE+8)
    const float* Xb = X + (size_t)b * N_PIX * FIN;
    for (int i = tid; i < XROWS * FIN; i += 512) {
        int r = i / FIN, f = i - r * FIN;
        int g = (n0 - 8 + r + N_PIX) & (N_PIX - 1);
        Xs[r * LDA + f] = Xb[(size_t)g * FIN + f];
    }
    __syncthreads();

    // T1 rows [n0-4, n0+TILE+4):  T1[g] = sum_j vals[9g+j] * X[g+j-4]
    for (int i = tid; i < T1ROWS * FIN; i += 512) {
        int r = i / FIN, f = i - r * FIN;
        int g = (n0 - 4 + r + N_PIX) & (N_PIX - 1);
        const float* vr = vals + (size_t)g * DEG;
        float acc = 0.f;
        #pragma unroll
        for (int j = 0; j < DEG; ++j)
            acc = fmaf(vr[j], Xs[(r + j) * LDA + f], acc);
        T1s[r * LDA + f] = acc;
    }
    __syncthreads();

    // T2 rows [n0, n0+TILE):  T2 = 2*L@T1 - T0
    for (int i = tid; i < TILE * FIN; i += 512) {
        int r = i / FIN, f = i - r * FIN;
        int g = n0 + r;
        const float* vr = vals + (size_t)g * DEG;
        float acc = 0.f;
        #pragma unroll
        for (int j = 0; j < DEG; ++j)
            acc = fmaf(vr[j], T1s[(r + j) * LDA + f], acc);
        T2s[r * LDA + f] = 2.f * acc - Xs[(r + 8) * LDA + f];
    }
    __syncthreads();

    if constexpr (FOUT == 64) {
        // 64x64 output tile; 2 f-groups of 256 threads, each 16x16 threads,
        // 4 rows x 4 cols per thread; groups split each f-segment in half.
        const int g   = tid >> 8;
        const int lid = tid & 255;
        const int ty = lid >> 4, tx = lid & 15;
        const int r0 = ty * 4, c0 = tx * 4;
        float acc[4][4] = {};
        const float* tbs[3] = { Xs + 8 * LDA, T1s + 4 * LDA, T2s };
        #pragma unroll
        for (int s = 0; s < 3; ++s) {
            const float* T = tbs[s];
            const float* Wseg = Ws + s * FIN * 64;
            #pragma unroll 2
            for (int f0 = g * FH; f0 < g * FH + FH; f0 += 4) {
                float a[4][4];
                #pragma unroll
                for (int i = 0; i < 4; ++i)
                    *(float4*)(a[i]) = *(const float4*)(T + (r0 + i) * LDA + f0);
                #pragma unroll
                for (int k = 0; k < 4; ++k) {
                    float wv[4];
                    *(float4*)wv = *(const float4*)(Wseg + (f0 + k) * 64 + c0);
                    #pragma unroll
                    for (int i = 0; i < 4; ++i)
                        #pragma unroll
                        for (int j = 0; j < 4; ++j)
                            acc[i][j] = fmaf(a[i][k], wv[j], acc[i][j]);
                }
            }
        }
        // combine the two f-groups
        if (g == 1) {
            float* dst = Red + lid * 16;
            #pragma unroll
            for (int i = 0; i < 4; ++i)
                #pragma unroll
                for (int j = 0; j < 4; ++j) dst[i * 4 + j] = acc[i][j];
        }
        __syncthreads();
        if (g == 0) {
            const float* src = Red + lid * 16;
            float* Yb = Y + ((size_t)b * N_PIX + n0) * 64;
            #pragma unroll
            for (int i = 0; i < 4; ++i) {
                float vv[4];
                #pragma unroll
                for (int j = 0; j < 4; ++j) {
                    float t = acc[i][j] + src[i * 4 + j] + Bs[c0 + j];
                    if constexpr (ELU) t = t > 0.f ? t : expm1f(t);
                    vv[j] = t;
                }
                *(float4*)(Yb + (size_t)(r0 + i) * 64 + c0) = *(const float4*)vv;
            }
        }
    } else {
        // FOUT == 2 (final layer): one thread per (row, out)
        if (tid < TILE * FOUT) {
            const int r = tid / FOUT, o = tid % FOUT;
            float acc = 0.f;
            const float* T0r = Xs  + (8 + r) * LDA;
            const float* T1r = T1s + (4 + r) * LDA;
            const float* T2r = T2s + r * LDA;
            for (int f = 0; f < FIN; ++f) {
                acc = fmaf(T0r[f], Ws[f * FOUT + o], acc);
                acc = fmaf(T1r[f], Ws[(FIN + f) * FOUT + o], acc);
                acc = fmaf(T2r[f], Ws[(2 * FIN + f) * FOUT + o], acc);
            }
            Y[((size_t)b * N_PIX + n0 + r) * FOUT + o] = acc + Bs[o];
        }
    }
}

extern "C" void kernel_launch(void* const* d_in, const int* in_sizes, int n_in,
                              void* d_out, int out_size, void* d_ws, size_t ws_size,
                              hipStream_t stream) {
    const float* x    = (const float*)d_in[0];
    // d_in[1]=rows, d_in[2]=cols: structured stencil, not needed
    const float* vals = (const float*)d_in[3];
    const float* W1 = (const float*)d_in[4];
    const float* b1 = (const float*)d_in[5];
    const float* W2 = (const float*)d_in[6];
    const float* b2 = (const float*)d_in[7];
    const float* W3 = (const float*)d_in[8];
    const float* b3 = (const float*)d_in[9];
    const float* W4 = (const float*)d_in[10];
    const float* b4 = (const float*)d_in[11];
    const float* W5 = (const float*)d_in[12];
    const float* b5 = (const float*)d_in[13];
    float* out = (float*)d_out;

    float* bufA = (float*)d_ws;
    float* bufB = bufA + (size_t)BATCH * N_PIX * 64;

    dim3 grid(N_PIX / TILE, BATCH);
    dim3 block(512);
    cheb_layer<8, 64, true><<<grid, block, 0, stream>>>(x,    vals, W1, b1, bufA);
    cheb_layer<64, 64, true><<<grid, block, 0, stream>>>(bufA, vals, W2, b2, bufB);
    cheb_layer<64, 64, true><<<grid, block, 0, stream>>>(bufB, vals, W3, b3, bufA);
    cheb_layer<64, 64, true><<<grid, block, 0, stream>>>(bufA, vals, W4, b4, bufB);
    cheb_layer<64, 2, false><<<grid, block, 0, stream>>>(bufB, vals, W5, b5, out);
}

// Round 2
// 408.948 us; speedup vs baseline: 2.0740x; 2.0740x over previous
//
#include <hip/hip_runtime.h>
#include <math.h>

#define N_PIX 32768
#define DEG 9
#define BATCH 8
#define TILE 64

typedef __attribute__((ext_vector_type(8))) short bf16x8;
typedef __attribute__((ext_vector_type(16))) float f32x16;

__device__ __forceinline__ unsigned short bf16_rn(float x) {
    unsigned int u = __builtin_bit_cast(unsigned int, x);
    u += 0x7fffu + ((u >> 16) & 1u);          // round-to-nearest-even
    return (unsigned short)(u >> 16);
}
__device__ __forceinline__ float bf16_to_f(unsigned short u) {
    unsigned int v = ((unsigned int)u) << 16;
    return __builtin_bit_cast(float, v);
}

// split x = hi + lo (both bf16), store 4 consecutive elements to hi/lo planes
__device__ __forceinline__ void store_split(unsigned short* ph, unsigned short* pl, float4 v) {
    ushort4 h, l;
    h.x = bf16_rn(v.x); l.x = bf16_rn(v.x - bf16_to_f(h.x));
    h.y = bf16_rn(v.y); l.y = bf16_rn(v.y - bf16_to_f(h.y));
    h.z = bf16_rn(v.z); l.z = bf16_rn(v.z - bf16_to_f(h.z));
    h.w = bf16_rn(v.w); l.w = bf16_rn(v.w - bf16_to_f(h.w));
    *(ushort4*)ph = h;
    *(ushort4*)pl = l;
}

// ---------------------------------------------------------------------------
// Weight prep: W [192][64] fp32 -> lane-order split-bf16 fragments.
// Layout (elements): idx = ((t*12 + s)*64 + lane)*8 + j
//   holds W[k][n], k = s*16 + (lane>>5)*8 + j, n = t*32 + (lane&31)
// hi plane at [0,12288), lo plane at [12288,24576). One block per layer.
// ---------------------------------------------------------------------------
__global__ void prep_wt(const float* __restrict__ W2, const float* __restrict__ W3,
                        const float* __restrict__ W4, unsigned short* __restrict__ out) {
    const float* W = (blockIdx.x == 0) ? W2 : (blockIdx.x == 1) ? W3 : W4;
    unsigned short* o = out + (size_t)blockIdx.x * 24576;
    for (int idx = threadIdx.x; idx < 12288; idx += 256) {
        int j = idx & 7;
        int lane = (idx >> 3) & 63;
        int rest = idx >> 9;          // t*12 + s
        int s = rest % 12, t = rest / 12;
        int k = s * 16 + (lane >> 5) * 8 + j;
        int n = t * 32 + (lane & 31);
        float x = W[k * 64 + n];
        unsigned short hi = bf16_rn(x);
        unsigned short lo = bf16_rn(x - bf16_to_f(hi));
        o[idx] = hi;
        o[12288 + idx] = lo;
    }
}

// ---------------------------------------------------------------------------
// Mid layer (FIN=64 -> FOUT=64), fused stencil + split-bf16 MFMA GEMM + ELU.
// LDS: Xs fp32 [80][68] (aliased as reduction scratch in GEMM), planes
// Th/Tl bf16 [72][200] (rows = tile rows -4..67; k: T0 0..63, T1 64..127,
// T2 128..191). 79.6 KB total -> 2 blocks/CU.
// ---------------------------------------------------------------------------
__global__ __launch_bounds__(512, 4)
void cheb_mid(const float* __restrict__ X, const float* __restrict__ vals,
              const unsigned short* __restrict__ Wt, const float* __restrict__ bias,
              float* __restrict__ Y) {
    __shared__ alignas(16) float Xs[80 * 68];             // also GEMM reduce scratch
    __shared__ alignas(16) unsigned short Th[72 * 200];
    __shared__ alignas(16) unsigned short Tl[72 * 200];
    __shared__ float Bs[64];

    const int tid = threadIdx.x;
    const int n0 = blockIdx.x * TILE;
    const int b  = blockIdx.y;
    const float* Xb = X + (size_t)b * N_PIX * 64;

    if (tid < 64) Bs[tid] = bias[tid];
    // stage X rows n0-8 .. n0+71 (Xs row = tile row + 8)
    for (int i = tid; i < 80 * 16; i += 512) {
        int r = i >> 4, c = (i & 15) << 2;
        int g = (n0 - 8 + r) & (N_PIX - 1);
        *(float4*)&Xs[r * 68 + c] = *(const float4*)&Xb[(size_t)g * 64 + c];
    }
    __syncthreads();

    // pass0: T0 planes (center rows -> plane rows 4..67, k 0..63)
    for (int i = tid; i < 1024; i += 512) {
        int r = i >> 4, f0 = (i & 15) << 2;
        float4 v = *(const float4*)&Xs[(r + 8) * 68 + f0];
        int off = (r + 4) * 200 + f0;
        store_split(&Th[off], &Tl[off], v);
    }
    // pass1: T1 plane rows 0..71 (tile rows -4..67), k 64..127
    for (int i = tid; i < 1152; i += 512) {
        int pr = i >> 4, f0 = (i & 15) << 2;
        int g = (n0 + pr - 4) & (N_PIX - 1);
        const float* vp = vals + (size_t)g * DEG;
        float4 a = {0.f, 0.f, 0.f, 0.f};
        #pragma unroll
        for (int j = 0; j < DEG; ++j) {
            float vj = vp[j];
            float4 xv = *(const float4*)&Xs[(pr + j) * 68 + f0];
            a.x = fmaf(vj, xv.x, a.x); a.y = fmaf(vj, xv.y, a.y);
            a.z = fmaf(vj, xv.z, a.z); a.w = fmaf(vj, xv.w, a.w);
        }
        int off = pr * 200 + 64 + f0;
        store_split(&Th[off], &Tl[off], a);
    }
    __syncthreads();

    // pass2: T2 = 2*L@T1 - T0, plane rows 4..67, k 128..191
    for (int i = tid; i < 1024; i += 512) {
        int r = i >> 4, f0 = (i & 15) << 2;
        const float* vp = vals + (size_t)(n0 + r) * DEG;
        float4 a = {0.f, 0.f, 0.f, 0.f};
        #pragma unroll
        for (int j = 0; j < DEG; ++j) {
            float vj = vp[j];
            int off = (r + j) * 200 + 64 + f0;
            ushort4 h = *(const ushort4*)&Th[off];
            ushort4 l = *(const ushort4*)&Tl[off];
            a.x = fmaf(vj, bf16_to_f(h.x) + bf16_to_f(l.x), a.x);
            a.y = fmaf(vj, bf16_to_f(h.y) + bf16_to_f(l.y), a.y);
            a.z = fmaf(vj, bf16_to_f(h.z) + bf16_to_f(l.z), a.z);
            a.w = fmaf(vj, bf16_to_f(h.w) + bf16_to_f(l.w), a.w);
        }
        float4 x0 = *(const float4*)&Xs[(r + 8) * 68 + f0];
        a.x = 2.f * a.x - x0.x; a.y = 2.f * a.y - x0.y;
        a.z = 2.f * a.z - x0.z; a.w = 2.f * a.w - x0.w;
        int off = (r + 4) * 200 + 128 + f0;
        store_split(&Th[off], &Tl[off], a);
    }
    __syncthreads();

    // GEMM: 8 waves; tile t = (rh,ch) of 32x32, K halved across wave pairs.
    {
        const int w = tid >> 6, lane = tid & 63;
        const int t = w & 3, kh = w >> 2;
        const int rh = t >> 1, ch = t & 1;
        const int m = lane & 31, half = lane >> 5;
        const int arow = (4 + rh * 32 + m) * 200;
        f32x16 acc = {};
        #pragma unroll
        for (int s = kh * 6; s < kh * 6 + 6; ++s) {
            const int widx = ((ch * 12 + s) * 64 + lane) * 8;
            bf16x8 bh = *(const bf16x8*)&Wt[widx];
            bf16x8 bl = *(const bf16x8*)&Wt[12288 + widx];
            bf16x8 ah = *(const bf16x8*)&Th[arow + s * 16 + half * 8];
            bf16x8 al = *(const bf16x8*)&Tl[arow + s * 16 + half * 8];
            acc = __builtin_amdgcn_mfma_f32_32x32x16_bf16(al, bh, acc, 0, 0, 0);
            acc = __builtin_amdgcn_mfma_f32_32x32x16_bf16(ah, bl, acc, 0, 0, 0);
            acc = __builtin_amdgcn_mfma_f32_32x32x16_bf16(ah, bh, acc, 0, 0, 0);
        }
        float* Red = Xs;  // Xs is dead now; 4 tiles * 1024 floats = 16 KB <= 21.7 KB
        if (kh == 1) {
            #pragma unroll
            for (int rg = 0; rg < 16; ++rg) Red[(t * 16 + rg) * 64 + lane] = acc[rg];
        }
        __syncthreads();
        if (kh == 0) {
            const int col = ch * 32 + m;
            float* Yb = Y + ((size_t)b * N_PIX + n0) * 64;
            #pragma unroll
            for (int rg = 0; rg < 16; ++rg) {
                int row = rh * 32 + (rg & 3) + 8 * (rg >> 2) + 4 * half;
                float v = acc[rg] + Red[(t * 16 + rg) * 64 + lane] + Bs[col];
                v = v > 0.f ? v : expm1f(v);
                Yb[(size_t)row * 64 + col] = v;
            }
        }
    }
}

// ---------------------------------------------------------------------------
// Original fp32 layer (kept for FIN=8 first layer and FOUT=2 last layer)
// ---------------------------------------------------------------------------
template<int FIN, int FOUT, bool ELU>
__global__ __launch_bounds__(512, 1)
void cheb_layer(const float* __restrict__ X, const float* __restrict__ vals,
                const float* __restrict__ W, const float* __restrict__ bias,
                float* __restrict__ Y) {
    constexpr int LDA = FIN + 4;
    constexpr int XROWS = TILE + 16;
    constexpr int T1ROWS = TILE + 8;
    constexpr int FH = FIN / 2;

    __shared__ alignas(16) float Xs[XROWS * LDA];
    __shared__ alignas(16) float T1s[T1ROWS * LDA];
    __shared__ alignas(16) float T2s[TILE * LDA];
    __shared__ alignas(16) float Ws[3 * FIN * FOUT];
    __shared__ alignas(16) float Red[256 * 16];
    __shared__ float Bs[FOUT > 0 ? FOUT : 1];

    const int tid = threadIdx.x;
    const int n0 = blockIdx.x * TILE;
    const int b  = blockIdx.y;

    for (int i = tid; i < 3 * FIN * FOUT; i += 512) Ws[i] = W[i];
    if (tid < FOUT) Bs[tid] = bias[tid];

    const float* Xb = X + (size_t)b * N_PIX * FIN;
    for (int i = tid; i < XROWS * FIN; i += 512) {
        int r = i / FIN, f = i - r * FIN;
        int g = (n0 - 8 + r + N_PIX) & (N_PIX - 1);
        Xs[r * LDA + f] = Xb[(size_t)g * FIN + f];
    }
    __syncthreads();

    for (int i = tid; i < T1ROWS * FIN; i += 512) {
        int r = i / FIN, f = i - r * FIN;
        int g = (n0 - 4 + r + N_PIX) & (N_PIX - 1);
        const float* vr = vals + (size_t)g * DEG;
        float acc = 0.f;
        #pragma unroll
        for (int j = 0; j < DEG; ++j)
            acc = fmaf(vr[j], Xs[(r + j) * LDA + f], acc);
        T1s[r * LDA + f] = acc;
    }
    __syncthreads();

    for (int i = tid; i < TILE * FIN; i += 512) {
        int r = i / FIN, f = i - r * FIN;
        int g = n0 + r;
        const float* vr = vals + (size_t)g * DEG;
        float acc = 0.f;
        #pragma unroll
        for (int j = 0; j < DEG; ++j)
            acc = fmaf(vr[j], T1s[(r + j) * LDA + f], acc);
        T2s[r * LDA + f] = 2.f * acc - Xs[(r + 8) * LDA + f];
    }
    __syncthreads();

    if constexpr (FOUT == 64) {
        const int g   = tid >> 8;
        const int lid = tid & 255;
        const int ty = lid >> 4, tx = lid & 15;
        const int r0 = ty * 4, c0 = tx * 4;
        float acc[4][4] = {};
        const float* tbs[3] = { Xs + 8 * LDA, T1s + 4 * LDA, T2s };
        #pragma unroll
        for (int s = 0; s < 3; ++s) {
            const float* T = tbs[s];
            const float* Wseg = Ws + s * FIN * 64;
            #pragma unroll 2
            for (int f0 = g * FH; f0 < g * FH + FH; f0 += 4) {
                float a[4][4];
                #pragma unroll
                for (int i = 0; i < 4; ++i)
                    *(float4*)(a[i]) = *(const float4*)(T + (r0 + i) * LDA + f0);
                #pragma unroll
                for (int k = 0; k < 4; ++k) {
                    float wv[4];
                    *(float4*)wv = *(const float4*)(Wseg + (f0 + k) * 64 + c0);
                    #pragma unroll
                    for (int i = 0; i < 4; ++i)
                        #pragma unroll
                        for (int j = 0; j < 4; ++j)
                            acc[i][j] = fmaf(a[i][k], wv[j], acc[i][j]);
                }
            }
        }
        if (g == 1) {
            float* dst = Red + lid * 16;
            #pragma unroll
            for (int i = 0; i < 4; ++i)
                #pragma unroll
                for (int j = 0; j < 4; ++j) dst[i * 4 + j] = acc[i][j];
        }
        __syncthreads();
        if (g == 0) {
            const float* src = Red + lid * 16;
            float* Yb = Y + ((size_t)b * N_PIX + n0) * 64;
            #pragma unroll
            for (int i = 0; i < 4; ++i) {
                float vv[4];
                #pragma unroll
                for (int j = 0; j < 4; ++j) {
                    float t = acc[i][j] + src[i * 4 + j] + Bs[c0 + j];
                    if constexpr (ELU) t = t > 0.f ? t : expm1f(t);
                    vv[j] = t;
                }
                *(float4*)(Yb + (size_t)(r0 + i) * 64 + c0) = *(const float4*)vv;
            }
        }
    } else {
        if (tid < TILE * FOUT) {
            const int r = tid / FOUT, o = tid % FOUT;
            float acc = 0.f;
            const float* T0r = Xs  + (8 + r) * LDA;
            const float* T1r = T1s + (4 + r) * LDA;
            const float* T2r = T2s + r * LDA;
            for (int f = 0; f < FIN; ++f) {
                acc = fmaf(T0r[f], Ws[f * FOUT + o], acc);
                acc = fmaf(T1r[f], Ws[(FIN + f) * FOUT + o], acc);
                acc = fmaf(T2r[f], Ws[(2 * FIN + f) * FOUT + o], acc);
            }
            Y[((size_t)b * N_PIX + n0 + r) * FOUT + o] = acc + Bs[o];
        }
    }
}

extern "C" void kernel_launch(void* const* d_in, const int* in_sizes, int n_in,
                              void* d_out, int out_size, void* d_ws, size_t ws_size,
                              hipStream_t stream) {
    const float* x    = (const float*)d_in[0];
    const float* vals = (const float*)d_in[3];
    const float* W1 = (const float*)d_in[4];
    const float* b1 = (const float*)d_in[5];
    const float* W2 = (const float*)d_in[6];
    const float* b2 = (const float*)d_in[7];
    const float* W3 = (const float*)d_in[8];
    const float* b3 = (const float*)d_in[9];
    const float* W4 = (const float*)d_in[10];
    const float* b4 = (const float*)d_in[11];
    const float* W5 = (const float*)d_in[12];
    const float* b5 = (const float*)d_in[13];
    float* out = (float*)d_out;

    float* bufA = (float*)d_ws;
    float* bufB = bufA + (size_t)BATCH * N_PIX * 64;

    // Wt scratch lives in d_out (3 * 48 KiB = 144 KiB << 2 MiB); the final
    // layer overwrites all of d_out afterwards, every launch.
    unsigned short* wt = (unsigned short*)d_out;

    dim3 grid(N_PIX / TILE, BATCH);
    prep_wt<<<dim3(3), dim3(256), 0, stream>>>(W2, W3, W4, wt);
    cheb_layer<8, 64, true><<<grid, dim3(512), 0, stream>>>(x, vals, W1, b1, bufA);
    cheb_mid<<<grid, dim3(512), 0, stream>>>(bufA, vals, wt,           b2, bufB);
    cheb_mid<<<grid, dim3(512), 0, stream>>>(bufB, vals, wt + 24576,   b3, bufA);
    cheb_mid<<<grid, dim3(512), 0, stream>>>(bufA, vals, wt + 49152,   b4, bufB);
    cheb_layer<64, 2, false><<<grid, dim3(512), 0, stream>>>(bufB, vals, W5, b5, out);
}

// Round 3
// 358.607 us; speedup vs baseline: 2.3652x; 1.1404x over previous
//
#include <hip/hip_runtime.h>
#include <math.h>

#define N_PIX 32768
#define DEG 9
#define BATCH 8
#define TILE 64

typedef __attribute__((ext_vector_type(8))) short bf16x8;
typedef __attribute__((ext_vector_type(16))) float f32x16;

__device__ __forceinline__ unsigned short bf16_rn(float x) {
    unsigned int u = __builtin_bit_cast(unsigned int, x);
    u += 0x7fffu + ((u >> 16) & 1u);
    return (unsigned short)(u >> 16);
}
__device__ __forceinline__ float bf16_to_f(unsigned short u) {
    unsigned int v = ((unsigned int)u) << 16;
    return __builtin_bit_cast(float, v);
}

// ---------------------------------------------------------------------------
// Weight prep (unchanged layout, verified in R2): W [192][64] fp32 ->
// lane-order split-bf16 fragments. idx = ((t*12+s)*64+lane)*8+j holds
// W[k][n], k = s*16+(lane>>5)*8+j, n = t*32+(lane&31). hi [0,12288),
// lo [12288,24576). grid (3 layers, 16 parts).
// ---------------------------------------------------------------------------
__global__ void prep_wt(const float* __restrict__ W2, const float* __restrict__ W3,
                        const float* __restrict__ W4, unsigned short* __restrict__ out) {
    const float* W = (blockIdx.x == 0) ? W2 : (blockIdx.x == 1) ? W3 : W4;
    unsigned short* o = out + (size_t)blockIdx.x * 24576;
    const int base = blockIdx.y * 768;
    for (int idx = base + threadIdx.x; idx < base + 768; idx += 256) {
        int j = idx & 7;
        int lane = (idx >> 3) & 63;
        int rest = idx >> 9;
        int s = rest % 12, t = rest / 12;
        int k = s * 16 + (lane >> 5) * 8 + j;
        int n = t * 32 + (lane & 31);
        float x = W[k * 64 + n];
        unsigned short hi = bf16_rn(x);
        unsigned short lo = bf16_rn(x - bf16_to_f(hi));
        o[idx] = hi;
        o[12288 + idx] = lo;
    }
}

// ---------------------------------------------------------------------------
// Mid layer v2: fp32 LDS T-planes, strip-mined f4 stencil, register bf16
// split at MFMA time. LDS ~61.6 KB -> 2 blocks/CU.
// ---------------------------------------------------------------------------
__global__ __launch_bounds__(512, 4)
void cheb_mid2(const float* __restrict__ X, const float* __restrict__ vals,
               const unsigned short* __restrict__ Wt, const float* __restrict__ bias,
               float* __restrict__ Y) {
    __shared__ alignas(16) float Xs[80 * 68];   // rows n0-8..n0+71 (also Red scratch)
    __shared__ alignas(16) float T1[72 * 68];   // rows n0-4..n0+67
    __shared__ alignas(16) float T2[64 * 68];   // rows n0..n0+63
    __shared__ alignas(16) float Vs[648];       // vals rows n0-4..n0+67, flat [72][9]
    __shared__ float Bs[64];

    const int tid = threadIdx.x;
    const int n0 = blockIdx.x * TILE;
    const int b  = blockIdx.y;
    const float* Xb = X + (size_t)b * N_PIX * 64;

    if (tid < 64) Bs[tid] = bias[tid];
    // stage X (f4) and vals
    for (int i = tid; i < 1280; i += 512) {
        int r = i >> 4, c = (i & 15) << 2;
        int g = (n0 - 8 + r) & (N_PIX - 1);
        *(float4*)&Xs[r * 68 + c] = *(const float4*)&Xb[(size_t)g * 64 + c];
    }
    for (int i = tid; i < 648; i += 512) {
        int v = i / 9;
        int g = (n0 - 4 + v) & (N_PIX - 1);
        Vs[i] = vals[(size_t)g * DEG + (i - v * 9)];
    }
    __syncthreads();

    // pass1: T1 rows 0..71 in strips of 3; 24 strips x 16 cols = 384 threads
    if (tid < 384) {
        const int st = tid >> 4, f0 = (tid & 15) << 2;
        const int r0 = st * 3;
        float4 xw[11];
        #pragma unroll
        for (int l = 0; l < 11; ++l)
            xw[l] = *(const float4*)&Xs[(r0 + l) * 68 + f0];
        #pragma unroll
        for (int r = 0; r < 3; ++r) {
            float4 a = {0.f, 0.f, 0.f, 0.f};
            #pragma unroll
            for (int j = 0; j < DEG; ++j) {
                float vj = Vs[(r0 + r) * 9 + j];
                float4 xv = xw[r + j];
                a.x = fmaf(vj, xv.x, a.x); a.y = fmaf(vj, xv.y, a.y);
                a.z = fmaf(vj, xv.z, a.z); a.w = fmaf(vj, xv.w, a.w);
            }
            *(float4*)&T1[(r0 + r) * 68 + f0] = a;
        }
    }
    __syncthreads();

    // pass2: T2 rows 0..63 in strips of 2; 32 strips x 16 cols = 512 threads
    {
        const int st = tid >> 4, f0 = (tid & 15) << 2;
        const int r0 = st * 2;
        float4 tw[10];
        #pragma unroll
        for (int l = 0; l < 10; ++l)
            tw[l] = *(const float4*)&T1[(r0 + l) * 68 + f0];
        #pragma unroll
        for (int r = 0; r < 2; ++r) {
            float4 a = {0.f, 0.f, 0.f, 0.f};
            #pragma unroll
            for (int j = 0; j < DEG; ++j) {
                float vj = Vs[(r0 + r + 4) * 9 + j];
                float4 xv = tw[r + j];
                a.x = fmaf(vj, xv.x, a.x); a.y = fmaf(vj, xv.y, a.y);
                a.z = fmaf(vj, xv.z, a.z); a.w = fmaf(vj, xv.w, a.w);
            }
            float4 x0 = *(const float4*)&Xs[(r0 + r + 8) * 68 + f0];
            a.x = 2.f * a.x - x0.x; a.y = 2.f * a.y - x0.y;
            a.z = 2.f * a.z - x0.z; a.w = 2.f * a.w - x0.w;
            *(float4*)&T2[(r0 + r) * 68 + f0] = a;
        }
    }
    __syncthreads();

    // GEMM: 8 waves; tile t=(rh,ch) 32x32, K halved across wave pairs (kh).
    {
        const int w = tid >> 6, lane = tid & 63;
        const int t = w & 3, kh = w >> 2;
        const int rh = t >> 1, ch = t & 1;
        const int m = lane & 31, half = lane >> 5;
        const int rt = rh * 32 + m;
        f32x16 acc = {};
        #pragma unroll
        for (int u = 0; u < 6; ++u) {
            const int s = kh * 6 + u;
            const int k0 = s * 16 + half * 8;
            const float* src;
            if (k0 < 64)       src = &Xs[(rt + 8) * 68 + k0];
            else if (k0 < 128) src = &T1[(rt + 4) * 68 + (k0 - 64)];
            else               src = &T2[rt * 68 + (k0 - 128)];
            float4 xa = *(const float4*)src;
            float4 xb = *(const float4*)(src + 4);
            float xf[8] = {xa.x, xa.y, xa.z, xa.w, xb.x, xb.y, xb.z, xb.w};
            bf16x8 ah, al;
            #pragma unroll
            for (int e = 0; e < 8; ++e) {
                unsigned short h = bf16_rn(xf[e]);
                ah[e] = (short)h;
                al[e] = (short)bf16_rn(xf[e] - bf16_to_f(h));
            }
            const int widx = ((ch * 12 + s) * 64 + lane) * 8;
            bf16x8 bh = *(const bf16x8*)&Wt[widx];
            bf16x8 bl = *(const bf16x8*)&Wt[12288 + widx];
            acc = __builtin_amdgcn_mfma_f32_32x32x16_bf16(al, bh, acc, 0, 0, 0);
            acc = __builtin_amdgcn_mfma_f32_32x32x16_bf16(ah, bl, acc, 0, 0, 0);
            acc = __builtin_amdgcn_mfma_f32_32x32x16_bf16(ah, bh, acc, 0, 0, 0);
        }
        float* Red = Xs;  // 4*1024 floats = 16 KB <= Xs size; barrier-protected
        __syncthreads();
        if (kh == 1) {
            #pragma unroll
            for (int rg = 0; rg < 16; ++rg) Red[(t * 16 + rg) * 64 + lane] = acc[rg];
        }
        __syncthreads();
        if (kh == 0) {
            const int col = ch * 32 + m;
            float* Yb = Y + ((size_t)b * N_PIX + n0) * 64;
            #pragma unroll
            for (int rg = 0; rg < 16; ++rg) {
                int row = rh * 32 + (rg & 3) + 8 * (rg >> 2) + 4 * half;
                float v = acc[rg] + Red[(t * 16 + rg) * 64 + lane] + Bs[col];
                v = v > 0.f ? v : expm1f(v);
                Yb[(size_t)row * 64 + col] = v;
            }
        }
    }
}

// ---------------------------------------------------------------------------
// Last layer via commute: P = X*[W0|W1|W2] (6 ch), S = P1 + 2 L P2,
// out = P0 - P2 + L S + b.  LDS ~30 KB -> 5 blocks/CU.
// ---------------------------------------------------------------------------
__global__ __launch_bounds__(512, 4)
void cheb_last(const float* __restrict__ X, const float* __restrict__ vals,
               const float* __restrict__ W5, const float* __restrict__ b5,
               float* __restrict__ Y) {
    __shared__ alignas(16) float Xs[80 * 68];
    __shared__ alignas(16) float Wst[384];   // [o][k], k=0..191
    __shared__ alignas(16) float Pb[80 * 8]; // [r][s*2+o]
    __shared__ alignas(16) float Sb[72 * 4]; // [r][o]
    __shared__ alignas(16) float Vs[648];
    __shared__ float Bs[2];

    const int tid = threadIdx.x;
    const int n0 = blockIdx.x * TILE;
    const int b  = blockIdx.y;
    const float* Xb = X + (size_t)b * N_PIX * 64;

    if (tid < 2) Bs[tid] = b5[tid];
    if (tid < 384) { int k = tid >> 1, o = tid & 1; Wst[o * 192 + k] = W5[tid]; }
    for (int i = tid; i < 1280; i += 512) {
        int r = i >> 4, c = (i & 15) << 2;
        int g = (n0 - 8 + r) & (N_PIX - 1);
        *(float4*)&Xs[r * 68 + c] = *(const float4*)&Xb[(size_t)g * 64 + c];
    }
    for (int i = tid; i < 648; i += 512) {
        int v = i / 9;
        int g = (n0 - 4 + v) & (N_PIX - 1);
        Vs[i] = vals[(size_t)g * DEG + (i - v * 9)];
    }
    __syncthreads();

    // P: 80 rows x 3 segs x 2 outs = 480 threads
    if (tid < 480) {
        const int r = tid / 6, rem = tid - r * 6;
        const int s = rem >> 1, o = rem & 1;
        const float* wcol = &Wst[o * 192 + s * 64];
        float acc = 0.f;
        #pragma unroll 4
        for (int q = 0; q < 16; ++q) {
            float4 xv = *(const float4*)&Xs[r * 68 + q * 4];
            float4 wv = *(const float4*)&wcol[q * 4];
            acc = fmaf(xv.x, wv.x, acc); acc = fmaf(xv.y, wv.y, acc);
            acc = fmaf(xv.z, wv.z, acc); acc = fmaf(xv.w, wv.w, acc);
        }
        Pb[r * 8 + s * 2 + o] = acc;
    }
    __syncthreads();

    // S rows 0..71 (global n0-4+sr): S = P1 + 2 * (L P2)
    if (tid < 144) {
        const int sr = tid >> 1, o = tid & 1;
        float q = 0.f;
        #pragma unroll
        for (int j = 0; j < DEG; ++j)
            q = fmaf(Vs[sr * 9 + j], Pb[(sr + j) * 8 + 4 + o], q);
        Sb[sr * 4 + o] = Pb[(sr + 4) * 8 + 2 + o] + 2.f * q;
    }
    __syncthreads();

    // out rows 0..63: out = P0 - P2 + L S + b
    if (tid < 128) {
        const int r = tid >> 1, o = tid & 1;
        float q = 0.f;
        #pragma unroll
        for (int j = 0; j < DEG; ++j)
            q = fmaf(Vs[(r + 4) * 9 + j], Sb[(r + j) * 4 + o], q);
        float v = Pb[(r + 8) * 8 + o] - Pb[(r + 8) * 8 + 4 + o] + q + Bs[o];
        Y[((size_t)b * N_PIX + n0 + r) * 2 + o] = v;
    }
}

// ---------------------------------------------------------------------------
// First layer (FIN=8), f4-vectorized fp32 path.
// ---------------------------------------------------------------------------
__global__ __launch_bounds__(512, 8)
void cheb_first(const float* __restrict__ X, const float* __restrict__ vals,
                const float* __restrict__ W, const float* __restrict__ bias,
                float* __restrict__ Y) {
    constexpr int LDA = 12;
    __shared__ alignas(16) float Xs[80 * LDA];
    __shared__ alignas(16) float T1s[72 * LDA];
    __shared__ alignas(16) float T2s[64 * LDA];
    __shared__ alignas(16) float Ws[24 * 64];
    __shared__ alignas(16) float Red[256 * 16];
    __shared__ float Bs[64];

    const int tid = threadIdx.x;
    const int n0 = blockIdx.x * TILE;
    const int b  = blockIdx.y;

    for (int i = tid; i < 24 * 64; i += 512) Ws[i] = W[i];
    if (tid < 64) Bs[tid] = bias[tid];

    const float* Xb = X + (size_t)b * N_PIX * 8;
    for (int i = tid; i < 160; i += 512) {
        int r = i >> 1, h = (i & 1) << 2;
        int g = (n0 - 8 + r) & (N_PIX - 1);
        *(float4*)&Xs[r * LDA + h] = *(const float4*)&Xb[(size_t)g * 8 + h];
    }
    __syncthreads();

    if (tid < 144) {
        int r = tid >> 1, h = (tid & 1) << 2;
        int g = (n0 - 4 + r) & (N_PIX - 1);
        const float* vr = vals + (size_t)g * DEG;
        float4 a = {0.f, 0.f, 0.f, 0.f};
        #pragma unroll
        for (int j = 0; j < DEG; ++j) {
            float vj = vr[j];
            float4 xv = *(const float4*)&Xs[(r + j) * LDA + h];
            a.x = fmaf(vj, xv.x, a.x); a.y = fmaf(vj, xv.y, a.y);
            a.z = fmaf(vj, xv.z, a.z); a.w = fmaf(vj, xv.w, a.w);
        }
        *(float4*)&T1s[r * LDA + h] = a;
    }
    __syncthreads();

    if (tid < 128) {
        int r = tid >> 1, h = (tid & 1) << 2;
        const float* vr = vals + (size_t)(n0 + r) * DEG;
        float4 a = {0.f, 0.f, 0.f, 0.f};
        #pragma unroll
        for (int j = 0; j < DEG; ++j) {
            float vj = vr[j];
            float4 xv = *(const float4*)&T1s[(r + j) * LDA + h];
            a.x = fmaf(vj, xv.x, a.x); a.y = fmaf(vj, xv.y, a.y);
            a.z = fmaf(vj, xv.z, a.z); a.w = fmaf(vj, xv.w, a.w);
        }
        float4 x0 = *(const float4*)&Xs[(r + 8) * LDA + h];
        a.x = 2.f * a.x - x0.x; a.y = 2.f * a.y - x0.y;
        a.z = 2.f * a.z - x0.z; a.w = 2.f * a.w - x0.w;
        *(float4*)&T2s[r * LDA + h] = a;
    }
    __syncthreads();

    // fp32 GEMM [64 x 24] @ [24 x 64]; 2 groups of 256 threads split f-range
    {
        const int g   = tid >> 8;
        const int lid = tid & 255;
        const int ty = lid >> 4, tx = lid & 15;
        const int r0 = ty * 4, c0 = tx * 4;
        float acc[4][4] = {};
        const float* tbs[3] = { Xs + 8 * LDA, T1s + 4 * LDA, T2s };
        #pragma unroll
        for (int s = 0; s < 3; ++s) {
            const float* T = tbs[s];
            const float* Wseg = Ws + s * 8 * 64;
            const int f0 = g * 4;
            float a[4][4];
            #pragma unroll
            for (int i = 0; i < 4; ++i)
                *(float4*)(a[i]) = *(const float4*)(T + (r0 + i) * LDA + f0);
            #pragma unroll
            for (int k = 0; k < 4; ++k) {
                float wv[4];
                *(float4*)wv = *(const float4*)(Wseg + (f0 + k) * 64 + c0);
                #pragma unroll
                for (int i = 0; i < 4; ++i)
                    #pragma unroll
                    for (int j = 0; j < 4; ++j)
                        acc[i][j] = fmaf(a[i][k], wv[j], acc[i][j]);
            }
        }
        if (g == 1) {
            float* dst = Red + lid * 16;
            #pragma unroll
            for (int i = 0; i < 4; ++i)
                #pragma unroll
                for (int j = 0; j < 4; ++j) dst[i * 4 + j] = acc[i][j];
        }
        __syncthreads();
        if (g == 0) {
            const float* src = Red + lid * 16;
            float* Yb = Y + ((size_t)b * N_PIX + n0) * 64;
            #pragma unroll
            for (int i = 0; i < 4; ++i) {
                float vv[4];
                #pragma unroll
                for (int j = 0; j < 4; ++j) {
                    float t = acc[i][j] + src[i * 4 + j] + Bs[c0 + j];
                    t = t > 0.f ? t : expm1f(t);
                    vv[j] = t;
                }
                *(float4*)(Yb + (size_t)(r0 + i) * 64 + c0) = *(const float4*)vv;
            }
        }
    }
}

extern "C" void kernel_launch(void* const* d_in, const int* in_sizes, int n_in,
                              void* d_out, int out_size, void* d_ws, size_t ws_size,
                              hipStream_t stream) {
    const float* x    = (const float*)d_in[0];
    const float* vals = (const float*)d_in[3];
    const float* W1 = (const float*)d_in[4];
    const float* b1 = (const float*)d_in[5];
    const float* W2 = (const float*)d_in[6];
    const float* b2 = (const float*)d_in[7];
    const float* W3 = (const float*)d_in[8];
    const float* b3 = (const float*)d_in[9];
    const float* W4 = (const float*)d_in[10];
    const float* b4 = (const float*)d_in[11];
    const float* W5 = (const float*)d_in[12];
    const float* b5 = (const float*)d_in[13];
    float* out = (float*)d_out;

    float* bufA = (float*)d_ws;
    float* bufB = bufA + (size_t)BATCH * N_PIX * 64;

    unsigned short* wt = (unsigned short*)d_out;  // scratch; overwritten by cheb_last

    dim3 grid(N_PIX / TILE, BATCH);
    prep_wt<<<dim3(3, 16), dim3(256), 0, stream>>>(W2, W3, W4, wt);
    cheb_first<<<grid, dim3(512), 0, stream>>>(x, vals, W1, b1, bufA);
    cheb_mid2<<<grid, dim3(512), 0, stream>>>(bufA, vals, wt,         b2, bufB);
    cheb_mid2<<<grid, dim3(512), 0, stream>>>(bufB, vals, wt + 24576, b3, bufA);
    cheb_mid2<<<grid, dim3(512), 0, stream>>>(bufA, vals, wt + 49152, b4, bufB);
    cheb_last<<<grid, dim3(512), 0, stream>>>(bufB, vals, W5, b5, out);
}

// Round 4
// 345.220 us; speedup vs baseline: 2.4569x; 1.0388x over previous
//
#include <hip/hip_runtime.h>
#include <math.h>

#define N_PIX 32768
#define DEG 9
#define BATCH 8
#define TILE 64

typedef unsigned short u16;
typedef __attribute__((ext_vector_type(8))) short bf16x8;
typedef __attribute__((ext_vector_type(16))) float f32x16;

__device__ __forceinline__ u16 bf16_rn(float x) {
    unsigned int u = __builtin_bit_cast(unsigned int, x);
    u += 0x7fffu + ((u >> 16) & 1u);
    return (u16)(u >> 16);
}
__device__ __forceinline__ float bf16_to_f(u16 u) {
    unsigned int v = ((unsigned int)u) << 16;
    return __builtin_bit_cast(float, v);
}

// ---------------------------------------------------------------------------
// Weight prep: from W [192][64] build three 64x64 matrices (W0-W2, W1, W2) in
// lane-order split-bf16 frags. idx = ((mat*2+t)*4+s)*512 + lane*8 + j holds
// M[k][n], k = s*16+(lane>>5)*8+j, n = t*32+(lane&31). hi [0,12288), lo +12288.
// ---------------------------------------------------------------------------
__global__ void prep_wt(const float* __restrict__ W2, const float* __restrict__ W3,
                        const float* __restrict__ W4, u16* __restrict__ out) {
    const float* W = (blockIdx.x == 0) ? W2 : (blockIdx.x == 1) ? W3 : W4;
    u16* o = out + (size_t)blockIdx.x * 24576;
    const int base = blockIdx.y * 768;
    for (int idx = base + threadIdx.x; idx < base + 768; idx += 256) {
        int j = idx & 7;
        int lane = (idx >> 3) & 63;
        int rest = idx >> 9;            // (mat*2+t)*4+s
        int s = rest & 3, tt = rest >> 2;
        int t = tt & 1, mat = tt >> 1;
        int k = s * 16 + (lane >> 5) * 8 + j;
        int n = t * 32 + (lane & 31);
        float x = (mat == 0) ? W[k * 64 + n] - W[(128 + k) * 64 + n]
                : (mat == 1) ? W[(64 + k) * 64 + n]
                             : W[(128 + k) * 64 + n];
        u16 hi = bf16_rn(x);
        o[idx] = hi;
        o[12288 + idx] = bf16_rn(x - bf16_to_f(hi));
    }
}

// ---------------------------------------------------------------------------
// Mid layer: P0/P1/P2 = X*(W0-W2)/X*W1/X*W2 via split-bf16 MFMA (A from
// pre-split planes), then S = P1 + 2 L P2 (in place), Q = L S + b, epilogue
// Y = elu(P0 + Q) -> split planes. LDS 80768 B -> 2 blocks/CU.
// ---------------------------------------------------------------------------
__global__ __launch_bounds__(512, 4)
void cheb_mid3(const u16* __restrict__ Xh, const u16* __restrict__ Xl,
               const float* __restrict__ vals, const u16* __restrict__ Wt,
               const float* __restrict__ bias,
               u16* __restrict__ Yh, u16* __restrict__ Yl) {
    __shared__ alignas(16) u16 Ah[80 * 64];
    __shared__ alignas(16) u16 Al[80 * 64];
    __shared__ alignas(16) float P2s[80 * 68];   // later: Q
    __shared__ alignas(16) float P1s[72 * 64];   // later: S (in place)
    __shared__ alignas(16) float P0s[64 * 65];
    __shared__ alignas(16) float Vs[72 * 12];

    const int tid = threadIdx.x;
    const int n0 = blockIdx.x * TILE;
    const int b  = blockIdx.y;
    const u16* XhB = Xh + (size_t)b * N_PIX * 64;
    const u16* XlB = Xl + (size_t)b * N_PIX * 64;

    // stage split planes with XOR channel-block swizzle
    for (int i = tid; i < 640; i += 512) {
        int r = i >> 3, cb = i & 7;
        int g = (n0 - 8 + r) & (N_PIX - 1);
        int d = r * 64 + ((cb ^ (r & 7)) << 3);
        *(uint4*)&Ah[d] = *(const uint4*)&XhB[(size_t)g * 64 + cb * 8];
        *(uint4*)&Al[d] = *(const uint4*)&XlB[(size_t)g * 64 + cb * 8];
    }
    for (int i = tid; i < 648; i += 512) {
        int sr = i / 9, j = i - sr * 9;
        int g = (n0 - 4 + sr) & (N_PIX - 1);
        Vs[sr * 12 + j] = vals[(size_t)g * DEG + j];
    }
    __syncthreads();

    // ---- GEMM phase ----
    {
        const int w = tid >> 6, lane = tid & 63;
        const int m = lane & 31, half = lane >> 5;
        if (w < 6) {
            const int t = w & 1, mi_idx = w >> 1;
            const int mi = (mi_idx == 2) ? 48 : mi_idx * 32;
            const int row = mi + m;
            f32x16 acc1 = {}, acc2 = {};
            #pragma unroll
            for (int s = 0; s < 4; ++s) {
                int cb = s * 2 + half;
                int off = row * 64 + ((cb ^ (row & 7)) << 3);
                bf16x8 ah = *(const bf16x8*)&Ah[off];
                bf16x8 al = *(const bf16x8*)&Al[off];
                const u16* w1p = &Wt[((2 + t) * 4 + s) * 512 + lane * 8];
                const u16* w2p = &Wt[((4 + t) * 4 + s) * 512 + lane * 8];
                bf16x8 b1h = *(const bf16x8*)w1p;
                bf16x8 b1l = *(const bf16x8*)(w1p + 12288);
                bf16x8 b2h = *(const bf16x8*)w2p;
                bf16x8 b2l = *(const bf16x8*)(w2p + 12288);
                acc1 = __builtin_amdgcn_mfma_f32_32x32x16_bf16(al, b1h, acc1, 0, 0, 0);
                acc1 = __builtin_amdgcn_mfma_f32_32x32x16_bf16(ah, b1l, acc1, 0, 0, 0);
                acc1 = __builtin_amdgcn_mfma_f32_32x32x16_bf16(ah, b1h, acc1, 0, 0, 0);
                acc2 = __builtin_amdgcn_mfma_f32_32x32x16_bf16(al, b2h, acc2, 0, 0, 0);
                acc2 = __builtin_amdgcn_mfma_f32_32x32x16_bf16(ah, b2l, acc2, 0, 0, 0);
                acc2 = __builtin_amdgcn_mfma_f32_32x32x16_bf16(ah, b2h, acc2, 0, 0, 0);
            }
            const int col = t * 32 + m;
            #pragma unroll
            for (int rg = 0; rg < 16; ++rg) {
                int rr = mi + (rg & 3) + 8 * (rg >> 2) + 4 * half;
                P2s[rr * 68 + col] = acc2[rg];
                if (rr >= 4 && rr < 76) P1s[(rr - 4) * 64 + col] = acc1[rg];
            }
        } else {
            const int t = w - 6;
            #pragma unroll
            for (int item = 0; item < 2; ++item) {
                const int mi = item ? 40 : 8;
                const int row = mi + m;
                f32x16 acc = {};
                #pragma unroll
                for (int s = 0; s < 4; ++s) {
                    int cb = s * 2 + half;
                    int off = row * 64 + ((cb ^ (row & 7)) << 3);
                    bf16x8 ah = *(const bf16x8*)&Ah[off];
                    bf16x8 al = *(const bf16x8*)&Al[off];
                    const u16* w0p = &Wt[(t * 4 + s) * 512 + lane * 8];
                    bf16x8 b0h = *(const bf16x8*)w0p;
                    bf16x8 b0l = *(const bf16x8*)(w0p + 12288);
                    acc = __builtin_amdgcn_mfma_f32_32x32x16_bf16(al, b0h, acc, 0, 0, 0);
                    acc = __builtin_amdgcn_mfma_f32_32x32x16_bf16(ah, b0l, acc, 0, 0, 0);
                    acc = __builtin_amdgcn_mfma_f32_32x32x16_bf16(ah, b0h, acc, 0, 0, 0);
                }
                const int col = t * 32 + m;
                #pragma unroll
                for (int rg = 0; rg < 16; ++rg) {
                    int rr = mi + (rg & 3) + 8 * (rg >> 2) + 4 * half;
                    P0s[(rr - 8) * 65 + col] = acc[rg];
                }
            }
        }
    }
    __syncthreads();

    // ---- stencil1: S = P1 + 2 L P2, in place on P1s (rows = Xs 4..75) ----
    if (tid < 384) {
        const int st = tid >> 4, f0 = (tid & 15) << 2;
        float4 win[11];
        #pragma unroll
        for (int l = 0; l < 11; ++l)
            win[l] = *(const float4*)&P2s[(st * 3 + l) * 68 + f0];
        #pragma unroll
        for (int r = 0; r < 3; ++r) {
            const int br = st * 3 + r;
            float4 vA = *(const float4*)&Vs[br * 12];
            float4 vB = *(const float4*)&Vs[br * 12 + 4];
            float v8 = Vs[br * 12 + 8];
            float4 a = {0.f, 0.f, 0.f, 0.f};
            const float vj[9] = {vA.x, vA.y, vA.z, vA.w, vB.x, vB.y, vB.z, vB.w, v8};
            #pragma unroll
            for (int j = 0; j < 9; ++j) {
                float4 xv = win[r + j];
                a.x = fmaf(vj[j], xv.x, a.x); a.y = fmaf(vj[j], xv.y, a.y);
                a.z = fmaf(vj[j], xv.z, a.z); a.w = fmaf(vj[j], xv.w, a.w);
            }
            float4 p1 = *(const float4*)&P1s[br * 64 + f0];
            p1.x = fmaf(2.f, a.x, p1.x); p1.y = fmaf(2.f, a.y, p1.y);
            p1.z = fmaf(2.f, a.z, p1.z); p1.w = fmaf(2.f, a.w, p1.w);
            *(float4*)&P1s[br * 64 + f0] = p1;
        }
    }
    __syncthreads();

    // ---- stencil2: Q = L S + bias -> P2s rows 0..63 ----
    {
        const int st = tid >> 4, f0 = (tid & 15) << 2;
        const int r0 = st * 2;
        float4 win[10];
        #pragma unroll
        for (int l = 0; l < 10; ++l)
            win[l] = *(const float4*)&P1s[(r0 + l) * 64 + f0];
        const float4 bb = *(const float4*)&bias[f0];
        #pragma unroll
        for (int r = 0; r < 2; ++r) {
            const int br = r0 + r;
            float4 vA = *(const float4*)&Vs[(br + 4) * 12];
            float4 vB = *(const float4*)&Vs[(br + 4) * 12 + 4];
            float v8 = Vs[(br + 4) * 12 + 8];
            float4 a = bb;
            const float vj[9] = {vA.x, vA.y, vA.z, vA.w, vB.x, vB.y, vB.z, vB.w, v8};
            #pragma unroll
            for (int j = 0; j < 9; ++j) {
                float4 xv = win[r + j];
                a.x = fmaf(vj[j], xv.x, a.x); a.y = fmaf(vj[j], xv.y, a.y);
                a.z = fmaf(vj[j], xv.z, a.z); a.w = fmaf(vj[j], xv.w, a.w);
            }
            *(float4*)&P2s[br * 68 + f0] = a;
        }
    }
    __syncthreads();

    // ---- epilogue: Y = elu(P0 + Q) -> split planes ----
    {
        const int r = tid >> 3, c0 = (tid & 7) << 3;
        float4 qa = *(const float4*)&P2s[r * 68 + c0];
        float4 qb = *(const float4*)&P2s[r * 68 + c0 + 4];
        float y[8] = {qa.x, qa.y, qa.z, qa.w, qb.x, qb.y, qb.z, qb.w};
        #pragma unroll
        for (int i = 0; i < 8; ++i) {
            float v = y[i] + P0s[r * 65 + c0 + i];
            y[i] = v > 0.f ? v : expm1f(v);
        }
        unsigned int hw[4], lw[4];
        #pragma unroll
        for (int p = 0; p < 4; ++p) {
            u16 h0 = bf16_rn(y[2 * p]);
            u16 l0 = bf16_rn(y[2 * p] - bf16_to_f(h0));
            u16 h1 = bf16_rn(y[2 * p + 1]);
            u16 l1 = bf16_rn(y[2 * p + 1] - bf16_to_f(h1));
            hw[p] = (unsigned int)h0 | ((unsigned int)h1 << 16);
            lw[p] = (unsigned int)l0 | ((unsigned int)l1 << 16);
        }
        size_t base = ((size_t)b * N_PIX + n0 + r) * 64 + c0;
        *(uint4*)&Yh[base] = make_uint4(hw[0], hw[1], hw[2], hw[3]);
        *(uint4*)&Yl[base] = make_uint4(lw[0], lw[1], lw[2], lw[3]);
    }
}

// ---------------------------------------------------------------------------
// First layer (FIN=8): same commute skeleton, VALU GEMM (K=8), fp32 input.
// ---------------------------------------------------------------------------
__global__ __launch_bounds__(512, 4)
void cheb_first2(const float* __restrict__ X, const float* __restrict__ vals,
                 const float* __restrict__ W, const float* __restrict__ bias,
                 u16* __restrict__ Yh, u16* __restrict__ Yl) {
    __shared__ alignas(16) float X8[80 * 12];
    __shared__ alignas(16) float Wf[24 * 64];
    __shared__ alignas(16) float W0p[8 * 64];
    __shared__ alignas(16) float P2s[80 * 68];
    __shared__ alignas(16) float P1s[72 * 64];
    __shared__ alignas(16) float P0s[64 * 68];
    __shared__ alignas(16) float Vs[72 * 12];

    const int tid = threadIdx.x;
    const int n0 = blockIdx.x * TILE;
    const int b  = blockIdx.y;
    const float* Xb = X + (size_t)b * N_PIX * 8;

    for (int i = tid; i < 1536; i += 512) Wf[i] = W[i];
    for (int i = tid; i < 160; i += 512) {
        int r = i >> 1, h = (i & 1) << 2;
        int g = (n0 - 8 + r) & (N_PIX - 1);
        *(float4*)&X8[r * 12 + h] = *(const float4*)&Xb[(size_t)g * 8 + h];
    }
    for (int i = tid; i < 648; i += 512) {
        int sr = i / 9, j = i - sr * 9;
        int g = (n0 - 4 + sr) & (N_PIX - 1);
        Vs[sr * 12 + j] = vals[(size_t)g * DEG + j];
    }
    __syncthreads();
    W0p[tid & 511] = Wf[tid & 511] - Wf[1024 + (tid & 511)];
    __syncthreads();

    // P2 (80 rows), P1 (72), P0 (64) — VALU GEMM K=8
    for (int idx = tid; idx < 1280; idx += 512) {
        int row = idx >> 4, f0 = (idx & 15) << 2;
        float4 a = {0.f, 0.f, 0.f, 0.f};
        #pragma unroll
        for (int k = 0; k < 8; ++k) {
            float xv = X8[row * 12 + k];
            float4 wv = *(const float4*)&Wf[(16 + k) * 64 + f0];
            a.x = fmaf(xv, wv.x, a.x); a.y = fmaf(xv, wv.y, a.y);
            a.z = fmaf(xv, wv.z, a.z); a.w = fmaf(xv, wv.w, a.w);
        }
        *(float4*)&P2s[row * 68 + f0] = a;
    }
    for (int idx = tid; idx < 1152; idx += 512) {
        int br = idx >> 4, f0 = (idx & 15) << 2;
        float4 a = {0.f, 0.f, 0.f, 0.f};
        #pragma unroll
        for (int k = 0; k < 8; ++k) {
            float xv = X8[(br + 4) * 12 + k];
            float4 wv = *(const float4*)&Wf[(8 + k) * 64 + f0];
            a.x = fmaf(xv, wv.x, a.x); a.y = fmaf(xv, wv.y, a.y);
            a.z = fmaf(xv, wv.z, a.z); a.w = fmaf(xv, wv.w, a.w);
        }
        *(float4*)&P1s[br * 64 + f0] = a;
    }
    for (int idx = tid; idx < 1024; idx += 512) {
        int ry = idx >> 4, f0 = (idx & 15) << 2;
        float4 a = {0.f, 0.f, 0.f, 0.f};
        #pragma unroll
        for (int k = 0; k < 8; ++k) {
            float xv = X8[(ry + 8) * 12 + k];
            float4 wv = *(const float4*)&W0p[k * 64 + f0];
            a.x = fmaf(xv, wv.x, a.x); a.y = fmaf(xv, wv.y, a.y);
            a.z = fmaf(xv, wv.z, a.z); a.w = fmaf(xv, wv.w, a.w);
        }
        *(float4*)&P0s[ry * 68 + f0] = a;
    }
    __syncthreads();

    if (tid < 384) {
        const int st = tid >> 4, f0 = (tid & 15) << 2;
        float4 win[11];
        #pragma unroll
        for (int l = 0; l < 11; ++l)
            win[l] = *(const float4*)&P2s[(st * 3 + l) * 68 + f0];
        #pragma unroll
        for (int r = 0; r < 3; ++r) {
            const int br = st * 3 + r;
            float4 vA = *(const float4*)&Vs[br * 12];
            float4 vB = *(const float4*)&Vs[br * 12 + 4];
            float v8 = Vs[br * 12 + 8];
            float4 a = {0.f, 0.f, 0.f, 0.f};
            const float vj[9] = {vA.x, vA.y, vA.z, vA.w, vB.x, vB.y, vB.z, vB.w, v8};
            #pragma unroll
            for (int j = 0; j < 9; ++j) {
                float4 xv = win[r + j];
                a.x = fmaf(vj[j], xv.x, a.x); a.y = fmaf(vj[j], xv.y, a.y);
                a.z = fmaf(vj[j], xv.z, a.z); a.w = fmaf(vj[j], xv.w, a.w);
            }
            float4 p1 = *(const float4*)&P1s[br * 64 + f0];
            p1.x = fmaf(2.f, a.x, p1.x); p1.y = fmaf(2.f, a.y, p1.y);
            p1.z = fmaf(2.f, a.z, p1.z); p1.w = fmaf(2.f, a.w, p1.w);
            *(float4*)&P1s[br * 64 + f0] = p1;
        }
    }
    __syncthreads();

    {
        const int st = tid >> 4, f0 = (tid & 15) << 2;
        const int r0 = st * 2;
        float4 win[10];
        #pragma unroll
        for (int l = 0; l < 10; ++l)
            win[l] = *(const float4*)&P1s[(r0 + l) * 64 + f0];
        const float4 bb = *(const float4*)&bias[f0];
        #pragma unroll
        for (int r = 0; r < 2; ++r) {
            const int br = r0 + r;
            float4 vA = *(const float4*)&Vs[(br + 4) * 12];
            float4 vB = *(const float4*)&Vs[(br + 4) * 12 + 4];
            float v8 = Vs[(br + 4) * 12 + 8];
            float4 a = bb;
            const float vj[9] = {vA.x, vA.y, vA.z, vA.w, vB.x, vB.y, vB.z, vB.w, v8};
            #pragma unroll
            for (int j = 0; j < 9; ++j) {
                float4 xv = win[r + j];
                a.x = fmaf(vj[j], xv.x, a.x); a.y = fmaf(vj[j], xv.y, a.y);
                a.z = fmaf(vj[j], xv.z, a.z); a.w = fmaf(vj[j], xv.w, a.w);
            }
            *(float4*)&P2s[br * 68 + f0] = a;
        }
    }
    __syncthreads();

    {
        const int r = tid >> 3, c0 = (tid & 7) << 3;
        float4 qa = *(const float4*)&P2s[r * 68 + c0];
        float4 qb = *(const float4*)&P2s[r * 68 + c0 + 4];
        float4 pa = *(const float4*)&P0s[r * 68 + c0];
        float4 pb = *(const float4*)&P0s[r * 68 + c0 + 4];
        float y[8] = {qa.x + pa.x, qa.y + pa.y, qa.z + pa.z, qa.w + pa.w,
                      qb.x + pb.x, qb.y + pb.y, qb.z + pb.z, qb.w + pb.w};
        #pragma unroll
        for (int i = 0; i < 8; ++i) y[i] = y[i] > 0.f ? y[i] : expm1f(y[i]);
        unsigned int hw[4], lw[4];
        #pragma unroll
        for (int p = 0; p < 4; ++p) {
            u16 h0 = bf16_rn(y[2 * p]);
            u16 l0 = bf16_rn(y[2 * p] - bf16_to_f(h0));
            u16 h1 = bf16_rn(y[2 * p + 1]);
            u16 l1 = bf16_rn(y[2 * p + 1] - bf16_to_f(h1));
            hw[p] = (unsigned int)h0 | ((unsigned int)h1 << 16);
            lw[p] = (unsigned int)l0 | ((unsigned int)l1 << 16);
        }
        size_t base = ((size_t)b * N_PIX + n0 + r) * 64 + c0;
        *(uint4*)&Yh[base] = make_uint4(hw[0], hw[1], hw[2], hw[3]);
        *(uint4*)&Yl[base] = make_uint4(lw[0], lw[1], lw[2], lw[3]);
    }
}

// ---------------------------------------------------------------------------
// Last layer via commute (verified R3); input now split planes.
// ---------------------------------------------------------------------------
__global__ __launch_bounds__(512, 4)
void cheb_last(const u16* __restrict__ Xh, const u16* __restrict__ Xl,
               const float* __restrict__ vals,
               const float* __restrict__ W5, const float* __restrict__ b5,
               float* __restrict__ Y) {
    __shared__ alignas(16) float Xs[80 * 68];
    __shared__ alignas(16) float Wst[384];
    __shared__ alignas(16) float Pb[80 * 8];
    __shared__ alignas(16) float Sb[72 * 4];
    __shared__ alignas(16) float Vs[648];
    __shared__ float Bs[2];

    const int tid = threadIdx.x;
    const int n0 = blockIdx.x * TILE;
    const int b  = blockIdx.y;
    const u16* XhB = Xh + (size_t)b * N_PIX * 64;
    const u16* XlB = Xl + (size_t)b * N_PIX * 64;

    if (tid < 2) Bs[tid] = b5[tid];
    if (tid < 384) { int k = tid >> 1, o = tid & 1; Wst[o * 192 + k] = W5[tid]; }
    for (int i = tid; i < 640; i += 512) {
        int r = i >> 3, cb = i & 7;
        int g = (n0 - 8 + r) & (N_PIX - 1);
        const u16* hp = &XhB[(size_t)g * 64 + cb * 8];
        const u16* lp = &XlB[(size_t)g * 64 + cb * 8];
        ushort4 h0 = *(const ushort4*)hp, h1 = *(const ushort4*)(hp + 4);
        ushort4 l0 = *(const ushort4*)lp, l1 = *(const ushort4*)(lp + 4);
        float4 fa = {bf16_to_f(h0.x) + bf16_to_f(l0.x), bf16_to_f(h0.y) + bf16_to_f(l0.y),
                     bf16_to_f(h0.z) + bf16_to_f(l0.z), bf16_to_f(h0.w) + bf16_to_f(l0.w)};
        float4 fb = {bf16_to_f(h1.x) + bf16_to_f(l1.x), bf16_to_f(h1.y) + bf16_to_f(l1.y),
                     bf16_to_f(h1.z) + bf16_to_f(l1.z), bf16_to_f(h1.w) + bf16_to_f(l1.w)};
        *(float4*)&Xs[r * 68 + cb * 8] = fa;
        *(float4*)&Xs[r * 68 + cb * 8 + 4] = fb;
    }
    for (int i = tid; i < 648; i += 512) {
        int v = i / 9;
        int g = (n0 - 4 + v) & (N_PIX - 1);
        Vs[i] = vals[(size_t)g * DEG + (i - v * 9)];
    }
    __syncthreads();

    if (tid < 480) {
        const int r = tid / 6, rem = tid - r * 6;
        const int s = rem >> 1, o = rem & 1;
        const float* wcol = &Wst[o * 192 + s * 64];
        float acc = 0.f;
        #pragma unroll 4
        for (int q = 0; q < 16; ++q) {
            float4 xv = *(const float4*)&Xs[r * 68 + q * 4];
            float4 wv = *(const float4*)&wcol[q * 4];
            acc = fmaf(xv.x, wv.x, acc); acc = fmaf(xv.y, wv.y, acc);
            acc = fmaf(xv.z, wv.z, acc); acc = fmaf(xv.w, wv.w, acc);
        }
        Pb[r * 8 + s * 2 + o] = acc;
    }
    __syncthreads();

    if (tid < 144) {
        const int sr = tid >> 1, o = tid & 1;
        float q = 0.f;
        #pragma unroll
        for (int j = 0; j < DEG; ++j)
            q = fmaf(Vs[sr * 9 + j], Pb[(sr + j) * 8 + 4 + o], q);
        Sb[sr * 4 + o] = Pb[(sr + 4) * 8 + 2 + o] + 2.f * q;
    }
    __syncthreads();

    if (tid < 128) {
        const int r = tid >> 1, o = tid & 1;
        float q = 0.f;
        #pragma unroll
        for (int j = 0; j < DEG; ++j)
            q = fmaf(Vs[(r + 4) * 9 + j], Sb[(r + j) * 4 + o], q);
        float v = Pb[(r + 8) * 8 + o] - Pb[(r + 8) * 8 + 4 + o] + q + Bs[o];
        Y[((size_t)b * N_PIX + n0 + r) * 2 + o] = v;
    }
}

extern "C" void kernel_launch(void* const* d_in, const int* in_sizes, int n_in,
                              void* d_out, int out_size, void* d_ws, size_t ws_size,
                              hipStream_t stream) {
    const float* x    = (const float*)d_in[0];
    const float* vals = (const float*)d_in[3];
    const float* W1 = (const float*)d_in[4];
    const float* b1 = (const float*)d_in[5];
    const float* W2 = (const float*)d_in[6];
    const float* b2 = (const float*)d_in[7];
    const float* W3 = (const float*)d_in[8];
    const float* b3 = (const float*)d_in[9];
    const float* W4 = (const float*)d_in[10];
    const float* b4 = (const float*)d_in[11];
    const float* W5 = (const float*)d_in[12];
    const float* b5 = (const float*)d_in[13];
    float* out = (float*)d_out;

    const size_t PL = (size_t)BATCH * N_PIX * 64;  // 16,777,216 elems per plane
    u16* Ah_g = (u16*)d_ws;
    u16* Al_g = Ah_g + PL;
    u16* Bh_g = Ah_g + 2 * PL;
    u16* Bl_g = Ah_g + 3 * PL;
    u16* wt = (u16*)d_out;  // 144 KiB scratch; fully overwritten by cheb_last

    dim3 grid(N_PIX / TILE, BATCH);
    prep_wt<<<dim3(3, 16), dim3(256), 0, stream>>>(W2, W3, W4, wt);
    cheb_first2<<<grid, dim3(512), 0, stream>>>(x, vals, W1, b1, Ah_g, Al_g);
    cheb_mid3<<<grid, dim3(512), 0, stream>>>(Ah_g, Al_g, vals, wt,         b2, Bh_g, Bl_g);
    cheb_mid3<<<grid, dim3(512), 0, stream>>>(Bh_g, Bl_g, vals, wt + 24576, b3, Ah_g, Al_g);
    cheb_mid3<<<grid, dim3(512), 0, stream>>>(Ah_g, Al_g, vals, wt + 49152, b4, Bh_g, Bl_g);
    cheb_last<<<grid, dim3(512), 0, stream>>>(Bh_g, Bl_g, vals, W5, b5, out);
}

// Round 5
// 319.338 us; speedup vs baseline: 2.6560x; 1.0810x over previous
//
#include <hip/hip_runtime.h>
#include <math.h>

#define N_PIX 32768
#define DEG 9
#define BATCH 8
#define TILE 64

typedef unsigned short u16;
typedef __attribute__((ext_vector_type(8))) short bf16x8;
typedef __attribute__((ext_vector_type(16))) float f32x16;

__device__ __forceinline__ u16 bf16_rn(float x) {
    unsigned int u = __builtin_bit_cast(unsigned int, x);
    u += 0x7fffu + ((u >> 16) & 1u);
    return (u16)(u >> 16);
}
__device__ __forceinline__ float bf16_to_f(u16 u) {
    unsigned int v = ((unsigned int)u) << 16;
    return __builtin_bit_cast(float, v);
}

// Activation planes (split-bf16 hi/lo) use a B-frag-native chunked layout:
//   element (row g, ch c) at (g>>5)*2048 + (c>>3)*256 + (g&31)*8 + (c&7)
// so a GEMM B-fragment (32 rows x 8 ch) is one coalesced global dwordx4 load.

// ---------------------------------------------------------------------------
// Weight prep (mid layers): identical math/layout to R2-R4 (verified).
// idx = ((mat*2+mt)*4+s)*512 + lane*8 + j holds M[k][m], k=s*16+(lane>>5)*8+j,
// m = mt*32+(lane&31); mats: 0=W0-W2, 1=W1, 2=W2. hi at idx, lo at +12288.
// Interpreted as A-fragments of M^T for D = M^T X^T.
// ---------------------------------------------------------------------------
__global__ void prep_wt(const float* __restrict__ W2, const float* __restrict__ W3,
                        const float* __restrict__ W4, u16* __restrict__ out) {
    const float* W = (blockIdx.x == 0) ? W2 : (blockIdx.x == 1) ? W3 : W4;
    u16* o = out + (size_t)blockIdx.x * 24576;
    const int base = blockIdx.y * 768;
    for (int idx = base + threadIdx.x; idx < base + 768; idx += 256) {
        int j = idx & 7;
        int lane = (idx >> 3) & 63;
        int rest = idx >> 9;            // (mat*2+mt)*4+s
        int s = rest & 3, tt = rest >> 2;
        int mt = tt & 1, mat = tt >> 1;
        int k = s * 16 + (lane >> 5) * 8 + j;
        int m = mt * 32 + (lane & 31);
        float x = (mat == 0) ? W[k * 64 + m] - W[(128 + k) * 64 + m]
                : (mat == 1) ? W[(64 + k) * 64 + m]
                             : W[(128 + k) * 64 + m];
        u16 hi = bf16_rn(x);
        o[idx] = hi;
        o[12288 + idx] = bf16_rn(x - bf16_to_f(hi));
    }
}

// First-layer frags at u16 offset 73728: idx = (mat*2+mt)*4096 + lane*8 + j,
// K padded 8->16 (k>=8 -> 0). hi at idx, lo at +24576.
__global__ void prep_w1(const float* __restrict__ W1, u16* __restrict__ out) {
    u16* o = out + 73728;
    const int base = blockIdx.x * 1536;
    for (int e = base + threadIdx.x; e < base + 1536 && e < 24576; e += 256) {
        int j = e & 7;
        int lane = (e >> 3) & 63;
        int tt = e >> 12;               // mat*2+mt
        int mt = tt & 1, mat = tt >> 1;
        int m = mt * 32 + (lane & 31);
        float x = 0.f;
        if ((lane >> 5) == 0) {         // k = j < 8 valid
            x = (mat == 0) ? W1[j * 64 + m] - W1[(16 + j) * 64 + m]
              : (mat == 1) ? W1[(8 + j) * 64 + m]
                           : W1[(16 + j) * 64 + m];
        }
        u16 hi = bf16_rn(x);
        o[e] = hi;
        o[24576 + e] = bf16_rn(x - bf16_to_f(hi));
    }
}

// ---------------------------------------------------------------------------
// Fused ChebConv layer via commute: P0/P1/P2 = X*(W0-W2)/X*W1/X*W2 (MFMA,
// D = W^T X^T, scatter vectorized), S = P1 + 2 L P2, Y = elu(P0 + L S + b).
// LDS 62.2 KB -> 2 blocks/CU. Planes read/written in chunked global layout.
// ---------------------------------------------------------------------------
template<bool FIRST>
__global__ __launch_bounds__(512, 4)
void cheb_conv(const float* __restrict__ Xf, const u16* __restrict__ Xh,
               const u16* __restrict__ Xl, const float* __restrict__ vals,
               const u16* __restrict__ wt, int wbase, const float* __restrict__ bias,
               u16* __restrict__ Yh, u16* __restrict__ Yl) {
    __shared__ alignas(16) float P2s[80 * 68];
    __shared__ alignas(16) float P1s[72 * 68];
    __shared__ alignas(16) float P0s[64 * 68];
    __shared__ alignas(16) float Vs[72 * 12];

    const int tid = threadIdx.x;
    const int n0 = blockIdx.x * TILE;
    const int b  = blockIdx.y;
    const size_t bplane = (size_t)b * ((size_t)N_PIX * 64);

    for (int i = tid; i < 648; i += 512) {
        int sr = i / 9, j = i - sr * 9;
        int g = (n0 - 4 + sr) & (N_PIX - 1);
        Vs[sr * 12 + j] = vals[(size_t)g * DEG + j];
    }

    // ---- GEMM: 8 waves = 8 (matrix, n-tile) jobs, dual-m accs ----
    {
        const int w = tid >> 6, lane = tid & 63;
        const int half = lane >> 5, m31 = lane & 31;
        int mat, ntile, rowoff; float* dst;
        if (w < 3)      { mat = 2; ntile = (w == 0) ? 0 : ((w == 1) ? 32 : 48); rowoff = -8; dst = P2s; }
        else if (w < 6) { mat = 1; ntile = (w == 3) ? 0 : ((w == 4) ? 32 : 40); rowoff = -4; dst = P1s; }
        else            { mat = 0; ntile = (w == 6) ? 0 : 32;                   rowoff =  0; dst = P0s; }
        const int rl = ntile + m31;
        const int g = (n0 + rowoff + rl) & (N_PIX - 1);
        f32x16 acc0 = {}, acc1 = {};
        constexpr int SC   = FIRST ? 1 : 4;
        constexpr int LOFF = FIRST ? 24576 : 12288;
        const u16* a0p = wt + wbase + lane * 8 +
                         (FIRST ? (mat * 2) * 4096 : (mat * 2) * 4 * 512);
        const u16* a1p = a0p + (FIRST ? 4096 : 2048);
        const size_t bbase = bplane + (size_t)(g >> 5) * 2048 + (g & 31) * 8;
        const float* xfp = FIRST ? (Xf + (size_t)b * N_PIX * 8 + (size_t)g * 8) : nullptr;
        #pragma unroll
        for (int s = 0; s < SC; ++s) {
            bf16x8 bh = {}, bl = {};
            if constexpr (FIRST) {
                if (half == 0) {
                    float xv[8];
                    *(float4*)&xv[0] = *(const float4*)&xfp[0];
                    *(float4*)&xv[4] = *(const float4*)&xfp[4];
                    #pragma unroll
                    for (int e = 0; e < 8; ++e) {
                        u16 hh = bf16_rn(xv[e]);
                        bh[e] = (short)hh;
                        bl[e] = (short)bf16_rn(xv[e] - bf16_to_f(hh));
                    }
                }
            } else {
                const size_t off = bbase + (size_t)(s * 2 + half) * 256;
                bh = *(const bf16x8*)&Xh[off];
                bl = *(const bf16x8*)&Xl[off];
            }
            bf16x8 a0h = *(const bf16x8*)(a0p + s * 512);
            bf16x8 a0l = *(const bf16x8*)(a0p + s * 512 + LOFF);
            bf16x8 a1h = *(const bf16x8*)(a1p + s * 512);
            bf16x8 a1l = *(const bf16x8*)(a1p + s * 512 + LOFF);
            acc0 = __builtin_amdgcn_mfma_f32_32x32x16_bf16(a0l, bh, acc0, 0, 0, 0);
            acc0 = __builtin_amdgcn_mfma_f32_32x32x16_bf16(a0h, bl, acc0, 0, 0, 0);
            acc0 = __builtin_amdgcn_mfma_f32_32x32x16_bf16(a0h, bh, acc0, 0, 0, 0);
            acc1 = __builtin_amdgcn_mfma_f32_32x32x16_bf16(a1l, bh, acc1, 0, 0, 0);
            acc1 = __builtin_amdgcn_mfma_f32_32x32x16_bf16(a1h, bl, acc1, 0, 0, 0);
            acc1 = __builtin_amdgcn_mfma_f32_32x32x16_bf16(a1h, bh, acc1, 0, 0, 0);
        }
        // scatter: lane = row rl, regs 4q..4q+3 = ch {0..3} + 8q + 4*half
        #pragma unroll
        for (int q = 0; q < 4; ++q) {
            float4 v0 = {acc0[4 * q], acc0[4 * q + 1], acc0[4 * q + 2], acc0[4 * q + 3]};
            float4 v1 = {acc1[4 * q], acc1[4 * q + 1], acc1[4 * q + 2], acc1[4 * q + 3]};
            *(float4*)&dst[rl * 68 + q * 8 + half * 4]      = v0;
            *(float4*)&dst[rl * 68 + 32 + q * 8 + half * 4] = v1;
        }
    }
    __syncthreads();

    // ---- stencil1: S = P1 + 2 L P2 (in place on P1s), strips of 3 ----
    if (tid < 384) {
        const int st = tid >> 4, c0 = (tid & 15) << 2;
        const int r0 = st * 3;
        float4 win[11];
        #pragma unroll
        for (int l = 0; l < 11; ++l)
            win[l] = *(const float4*)&P2s[(r0 + l) * 68 + c0];
        #pragma unroll
        for (int r = 0; r < 3; ++r) {
            const int sg = r0 + r;
            float4 vA = *(const float4*)&Vs[sg * 12];
            float4 vB = *(const float4*)&Vs[sg * 12 + 4];
            float v8 = Vs[sg * 12 + 8];
            const float vj[9] = {vA.x, vA.y, vA.z, vA.w, vB.x, vB.y, vB.z, vB.w, v8};
            float4 a = {0.f, 0.f, 0.f, 0.f};
            #pragma unroll
            for (int j = 0; j < 9; ++j) {
                float4 xv = win[r + j];
                a.x = fmaf(vj[j], xv.x, a.x); a.y = fmaf(vj[j], xv.y, a.y);
                a.z = fmaf(vj[j], xv.z, a.z); a.w = fmaf(vj[j], xv.w, a.w);
            }
            float4 p1 = *(const float4*)&P1s[sg * 68 + c0];
            p1.x = fmaf(2.f, a.x, p1.x); p1.y = fmaf(2.f, a.y, p1.y);
            p1.z = fmaf(2.f, a.z, p1.z); p1.w = fmaf(2.f, a.w, p1.w);
            *(float4*)&P1s[sg * 68 + c0] = p1;
        }
    }
    __syncthreads();

    // ---- stencil2 + epilogue fused: Y = elu(P0 + L S + b), strips of 2 ----
    {
        const int st = tid >> 4, cx = tid & 15;
        const int y0 = st * 2, c0 = cx << 2;
        float4 win[10];
        #pragma unroll
        for (int l = 0; l < 10; ++l)
            win[l] = *(const float4*)&P1s[(y0 + l) * 68 + c0];
        const float4 bb = *(const float4*)&bias[c0];
        #pragma unroll
        for (int r = 0; r < 2; ++r) {
            const int y = y0 + r;
            float4 vA = *(const float4*)&Vs[(y + 4) * 12];
            float4 vB = *(const float4*)&Vs[(y + 4) * 12 + 4];
            float v8 = Vs[(y + 4) * 12 + 8];
            const float vj[9] = {vA.x, vA.y, vA.z, vA.w, vB.x, vB.y, vB.z, vB.w, v8};
            float4 a = bb;
            #pragma unroll
            for (int j = 0; j < 9; ++j) {
                float4 xv = win[r + j];
                a.x = fmaf(vj[j], xv.x, a.x); a.y = fmaf(vj[j], xv.y, a.y);
                a.z = fmaf(vj[j], xv.z, a.z); a.w = fmaf(vj[j], xv.w, a.w);
            }
            float4 p0 = *(const float4*)&P0s[y * 68 + c0];
            float yv[4] = {a.x + p0.x, a.y + p0.y, a.z + p0.z, a.w + p0.w};
            ushort4 h, l;
            u16 hh;
            #pragma unroll
            for (int e = 0; e < 4; ++e)
                yv[e] = yv[e] > 0.f ? yv[e] : expm1f(yv[e]);
            hh = bf16_rn(yv[0]); h.x = hh; l.x = bf16_rn(yv[0] - bf16_to_f(hh));
            hh = bf16_rn(yv[1]); h.y = hh; l.y = bf16_rn(yv[1] - bf16_to_f(hh));
            hh = bf16_rn(yv[2]); h.z = hh; l.z = bf16_rn(yv[2] - bf16_to_f(hh));
            hh = bf16_rn(yv[3]); h.w = hh; l.w = bf16_rn(yv[3] - bf16_to_f(hh));
            const int g = n0 + y;
            size_t dst = bplane + (size_t)(g >> 5) * 2048 + (size_t)(cx >> 1) * 256
                       + (g & 31) * 8 + (cx & 1) * 4;
            *(ushort4*)&Yh[dst] = h;
            *(ushort4*)&Yl[dst] = l;
        }
    }
}

// ---------------------------------------------------------------------------
// Last layer: P = X * W5_seg (6 ch) via MFMA from planes, then
// S = P1 + 2 L P2, out = P0 - P2 + L S + b.
// ---------------------------------------------------------------------------
__global__ __launch_bounds__(256, 4)
void cheb_last3(const u16* __restrict__ Xh, const u16* __restrict__ Xl,
                const float* __restrict__ vals,
                const float* __restrict__ W5, const float* __restrict__ b5,
                float* __restrict__ Y) {
    __shared__ alignas(16) float Pb[80 * 8];
    __shared__ alignas(16) float Sb[72 * 2];
    __shared__ alignas(16) float Vs[72 * 12];

    const int tid = threadIdx.x;
    const int n0 = blockIdx.x * TILE;
    const int b  = blockIdx.y;
    const size_t bplane = (size_t)b * ((size_t)N_PIX * 64);

    for (int i = tid; i < 648; i += 256) {
        int sr = i / 9, j = i - sr * 9;
        int g = (n0 - 4 + sr) & (N_PIX - 1);
        Vs[sr * 12 + j] = vals[(size_t)g * DEG + j];
    }

    {
        const int w = tid >> 6, lane = tid & 63;
        const int half = lane >> 5, m31 = lane & 31;
        if (w < 3) {
            const int ntile = (w == 0) ? 0 : ((w == 1) ? 32 : 48);
            const int rl = ntile + m31;
            const int g = (n0 - 8 + rl) & (N_PIX - 1);
            const size_t bbase = bplane + (size_t)(g >> 5) * 2048 + (g & 31) * 8;
            const bool valid = m31 < 6;
            const int seg = m31 >> 1, o = m31 & 1;
            f32x16 acc = {};
            #pragma unroll
            for (int s = 0; s < 4; ++s) {
                const size_t off = bbase + (size_t)(s * 2 + half) * 256;
                bf16x8 bh = *(const bf16x8*)&Xh[off];
                bf16x8 bl = *(const bf16x8*)&Xl[off];
                bf16x8 ah, al;
                #pragma unroll
                for (int j = 0; j < 8; ++j) {
                    int k = s * 16 + half * 8 + j;
                    float x = valid ? W5[(seg * 64 + k) * 2 + o] : 0.f;
                    u16 hh = bf16_rn(x);
                    ah[j] = (short)hh;
                    al[j] = (short)bf16_rn(x - bf16_to_f(hh));
                }
                acc = __builtin_amdgcn_mfma_f32_32x32x16_bf16(al, bh, acc, 0, 0, 0);
                acc = __builtin_amdgcn_mfma_f32_32x32x16_bf16(ah, bl, acc, 0, 0, 0);
                acc = __builtin_amdgcn_mfma_f32_32x32x16_bf16(ah, bh, acc, 0, 0, 0);
            }
            // D[m=c][n=row]: c = (rg&3)+8*(rg>>2)+4*half; keep c<6
            if (half == 0) {
                float4 v = {acc[0], acc[1], acc[2], acc[3]};
                *(float4*)&Pb[rl * 8] = v;           // c 0..3
            } else {
                Pb[rl * 8 + 4] = acc[0];             // c 4
                Pb[rl * 8 + 5] = acc[1];             // c 5
            }
        }
    }
    __syncthreads();

    // S = P1 + 2 L P2  (c: P0=0,1  P1=2,3  P2=4,5)
    if (tid < 144) {
        const int sg = tid >> 1, o = tid & 1;
        float q = 0.f;
        #pragma unroll
        for (int j = 0; j < DEG; ++j)
            q = fmaf(Vs[sg * 12 + j], Pb[(sg + j) * 8 + 4 + o], q);
        Sb[sg * 2 + o] = Pb[(sg + 4) * 8 + 2 + o] + 2.f * q;
    }
    __syncthreads();

    if (tid < 128) {
        const int y = tid >> 1, o = tid & 1;
        float q = 0.f;
        #pragma unroll
        for (int j = 0; j < DEG; ++j)
            q = fmaf(Vs[(y + 4) * 12 + j], Sb[(y + j) * 2 + o], q);
        float v = Pb[(y + 8) * 8 + o] - Pb[(y + 8) * 8 + 4 + o] + q + b5[o];
        Y[((size_t)b * N_PIX + n0 + y) * 2 + o] = v;
    }
}

extern "C" void kernel_launch(void* const* d_in, const int* in_sizes, int n_in,
                              void* d_out, int out_size, void* d_ws, size_t ws_size,
                              hipStream_t stream) {
    const float* x    = (const float*)d_in[0];
    const float* vals = (const float*)d_in[3];
    const float* W1 = (const float*)d_in[4];
    const float* b1 = (const float*)d_in[5];
    const float* W2 = (const float*)d_in[6];
    const float* b2 = (const float*)d_in[7];
    const float* W3 = (const float*)d_in[8];
    const float* b3 = (const float*)d_in[9];
    const float* W4 = (const float*)d_in[10];
    const float* b4 = (const float*)d_in[11];
    const float* W5 = (const float*)d_in[12];
    const float* b5 = (const float*)d_in[13];
    float* out = (float*)d_out;

    const size_t PL = (size_t)BATCH * N_PIX * 64;
    u16* Ah_g = (u16*)d_ws;
    u16* Al_g = Ah_g + PL;
    u16* Bh_g = Ah_g + 2 * PL;
    u16* Bl_g = Ah_g + 3 * PL;
    // weight-frag scratch in d_out (240 KiB << 2 MiB); all reads of it happen
    // in kernels that run strictly before cheb_last3 overwrites d_out.
    u16* wt = (u16*)d_out;

    dim3 grid(N_PIX / TILE, BATCH);
    prep_wt<<<dim3(3, 16), dim3(256), 0, stream>>>(W2, W3, W4, wt);
    prep_w1<<<dim3(16), dim3(256), 0, stream>>>(W1, wt);
    cheb_conv<true><<<grid, dim3(512), 0, stream>>>(x, nullptr, nullptr, vals, wt, 73728, b1, Ah_g, Al_g);
    cheb_conv<false><<<grid, dim3(512), 0, stream>>>(nullptr, Ah_g, Al_g, vals, wt, 0,     b2, Bh_g, Bl_g);
    cheb_conv<false><<<grid, dim3(512), 0, stream>>>(nullptr, Bh_g, Bl_g, vals, wt, 24576, b3, Ah_g, Al_g);
    cheb_conv<false><<<grid, dim3(512), 0, stream>>>(nullptr, Ah_g, Al_g, vals, wt, 49152, b4, Bh_g, Bl_g);
    cheb_last3<<<grid, dim3(256), 0, stream>>>(Bh_g, Bl_g, vals, W5, b5, out);
}